// Round 8
// baseline (505.988 us; speedup 1.0000x reference)
//
#include <hip/hip_runtime.h>
#include <hip/hip_bf16.h>
#include <stdint.h>

// ---------------------------------------------------------------------------
// NRI-style MLP encoder. B=32, T=50, N=100, D=4, E=9900, H=256. fp32 I/O.
// R7 formulation (send terms are node GEMMs; only edge GEMM is K=256 t2@Wpz).
// R8 changes (phaseB was VALU+occupancy bound: VALUBusy 28% top, Occ 21.5%):
//  - t2 A-frags built IN REGISTERS (relu(U+Hs) per kb) -> no stage0, no t2 LDS
//  - epilogue projection z4@(w4b@wo) via MFMA against 16-col padded Wfp
//    (z4 -> LDS C-layout round-trip) -> replaces ~900 VALU shfl-reduce
//  - Vs read from L2 in z4 formation -> LDS 59.9KB -> 33.8KB -> 4 blk/CU
//  - prep merged to 1 kernel -> 10 dispatches total
// ---------------------------------------------------------------------------

typedef __attribute__((ext_vector_type(8))) short short8;
typedef __attribute__((ext_vector_type(4))) float float4v;

__device__ inline float bf2f(unsigned short u) {
    union { unsigned int i; float f; } v; v.i = ((unsigned int)u) << 16; return v.f;
}
__device__ inline unsigned short f2bf(float f) {
    union { float f; unsigned int i; } v; v.f = f;
    unsigned int i = v.i;
    return (unsigned short)((i + 0x7FFFu + ((i >> 16) & 1u)) >> 16);
}

// ---------------------------------------------------------------------------
// MEGA-PREP: bx<2272 weight packs | <2528 Wpz=pack(w2b@w4a_e) | <2530 misc
// (Wfp/bfv/b4ap/b2bs) | rest repack x. fp32 in, bf16 packed out.
// Wp layout: Wp[kb][n][kk], kb=k/32, kk=k%32.
// Wfp layout: [kb][n16][kk32], cols 0..3 = w4b@wo, 4..15 = 0.
// ---------------------------------------------------------------------------
__global__ __launch_bounds__(256) void prep_kernel(
        const float* __restrict__ x,
        const float* __restrict__ w1a, const float* __restrict__ w1b,
        const float* __restrict__ w2a, const float* __restrict__ w2b,
        const float* __restrict__ w3a, const float* __restrict__ w3b,
        const float* __restrict__ w4a, const float* __restrict__ b4a,
        const float* __restrict__ w4b, const float* __restrict__ b4b,
        const float* __restrict__ wo,  const float* __restrict__ bo,
        const float* __restrict__ b2b,
        unsigned short* __restrict__ Wp1a, unsigned short* __restrict__ Wp1b,
        unsigned short* __restrict__ Wp2r, unsigned short* __restrict__ Wp2s,
        unsigned short* __restrict__ Wp2b, unsigned short* __restrict__ Wp3a,
        unsigned short* __restrict__ Wp3b, unsigned short* __restrict__ Wp4r,
        unsigned short* __restrict__ Wp4s, unsigned short* __restrict__ Wpz,
        unsigned short* __restrict__ Wfp, float* __restrict__ bfv,
        float* __restrict__ b4ap, float* __restrict__ b2bs,
        unsigned short* __restrict__ hin) {
    int bx = blockIdx.x;
    int tid = threadIdx.x;
    if (bx < 2272) {
        const float* W; unsigned short* Wp; int Kin; int b0;
        if      (bx <  224) { W = w1a;             Wp = Wp1a; Kin = 200; b0 = 0;    }
        else if (bx <  480) { W = w1b;             Wp = Wp1b; Kin = 256; b0 = 224;  }
        else if (bx <  736) { W = w2a;             Wp = Wp2r; Kin = 256; b0 = 480;  }
        else if (bx <  992) { W = w2a + 256 * 256; Wp = Wp2s; Kin = 256; b0 = 736;  }
        else if (bx < 1248) { W = w2b;             Wp = Wp2b; Kin = 256; b0 = 992;  }
        else if (bx < 1504) { W = w3a;             Wp = Wp3a; Kin = 256; b0 = 1248; }
        else if (bx < 1760) { W = w3b;             Wp = Wp3b; Kin = 256; b0 = 1504; }
        else if (bx < 2016) { W = w4a;             Wp = Wp4r; Kin = 256; b0 = 1760; }
        else                { W = w4a + 256 * 256; Wp = Wp4s; Kin = 256; b0 = 2016; }
        int idx = (bx - b0) * 256 + tid;
        int k = idx >> 8, n = idx & 255;
        unsigned short v = (k < Kin) ? f2bf(W[k * 256 + n]) : (unsigned short)0;
        Wp[((size_t)(k >> 5) * 256 + n) * 32 + (k & 31)] = v;
    } else if (bx < 2528) {
        int k = bx - 2272, c = tid;
        float s = 0.f;
        for (int t = 0; t < 256; ++t)
            s += w2b[k * 256 + t] * w4a[(size_t)(512 + t) * 256 + c];
        Wpz[((size_t)(k >> 5) * 256 + c) * 32 + (k & 31)] = f2bf(s);
    } else if (bx < 2530) {
        int k = tid;
        if (bx == 2528) {
            float a[4] = {0.f, 0.f, 0.f, 0.f};
            for (int c = 0; c < 256; ++c) {
                float wv = w4b[k * 256 + c];
                #pragma unroll
                for (int o = 0; o < 4; ++o) a[o] += wv * wo[c * 4 + o];
            }
            #pragma unroll
            for (int n = 0; n < 16; ++n)
                Wfp[(size_t)(k >> 5) * 512 + n * 32 + (k & 31)] =
                    (n < 4) ? f2bf(a[n]) : (unsigned short)0;
            if (k < 4) {
                float s = bo[k];
                for (int c = 0; c < 256; ++c) s += b4b[c] * wo[c * 4 + k];
                bfv[k] = s;
            }
        } else {
            float s = b4a[k];
            for (int t = 0; t < 256; ++t)
                s += b2b[t] * w4a[(size_t)(512 + t) * 256 + k];
            b4ap[k] = s;
            b2bs[k] = 0.99f * b2b[k];
        }
    } else {
        int idx = (bx - 2530) * 256 + tid;
        if (idx < 3200 * 224) {
            int row = idx / 224;
            int c = idx - row * 224;
            int b = row / 100, n = row - b * 100;
            unsigned short v = 0;
            if (c < 200) {
                int t = c >> 2, d = c & 3;
                v = f2bf(x[(((size_t)(b * 50 + t)) * 100 + n) * 4 + d]);
            }
            hin[(size_t)row * 224 + c] = v;
        }
    }
}

// ---------------------------------------------------------------------------
// Node GEMM: C = act(A@Wp + bias). Grid (100,4), block 128.
// ---------------------------------------------------------------------------
template <bool RELU>
__global__ __launch_bounds__(128) void node_gemm_kernel(
        const unsigned short* __restrict__ A,
        const unsigned short* __restrict__ Bp,
        const float* __restrict__ bias,
        unsigned short* __restrict__ C, int K) {
    const int tid  = threadIdx.x;
    const int wave = tid >> 6;
    const int lane = tid & 63;
    const int l15  = lane & 15;
    const int quad = lane >> 4;
    const int m0   = blockIdx.x * 32 + wave * 16;
    const int n0   = blockIdx.y * 64;
    const int koff = quad * 8;

    float4v acc[4];
    #pragma unroll
    for (int ni = 0; ni < 4; ++ni) acc[ni] = (float4v)(0.0f);

    const int KB = K >> 5;
    for (int kb = 0; kb < KB; ++kb) {
        short8 af = *(const short8*)(A + (size_t)(m0 + l15) * K + kb * 32 + koff);
        short8 bf[4];
        #pragma unroll
        for (int ni = 0; ni < 4; ++ni)
            bf[ni] = *(const short8*)(Bp + ((size_t)kb * 256 + n0 + ni * 16 + l15) * 32 + koff);
        #pragma unroll
        for (int ni = 0; ni < 4; ++ni)
            acc[ni] = __builtin_amdgcn_mfma_f32_16x16x32_bf16(af, bf[ni], acc[ni], 0, 0, 0);
    }

    #pragma unroll
    for (int ni = 0; ni < 4; ++ni) {
        int col = n0 + ni * 16 + l15;
        float bv = bias[col];
        #pragma unroll
        for (int r = 0; r < 4; ++r) {
            float v = acc[ni][r] + bv;
            if (RELU) v = v > 0.f ? v : 0.f;
            C[(size_t)(m0 + quad * 4 + r) * 256 + col] = f2bf(v);
        }
    }
}

// ---- dual node GEMM (shared A, K=256): y<4 -> C0=A@Bp0+bias0; y>=4 -> C1=A@Bp1 ----
__global__ __launch_bounds__(128) void node_gemm_dual_kernel(
        const unsigned short* __restrict__ A,
        const unsigned short* __restrict__ Bp0, const float* __restrict__ bias0,
        unsigned short* __restrict__ C0,
        const unsigned short* __restrict__ Bp1, unsigned short* __restrict__ C1) {
    const int tid  = threadIdx.x;
    const int wave = tid >> 6;
    const int lane = tid & 63;
    const int l15  = lane & 15;
    const int quad = lane >> 4;
    const int m0   = blockIdx.x * 32 + wave * 16;
    const int sel  = blockIdx.y >> 2;
    const int n0   = (blockIdx.y & 3) * 64;
    const int koff = quad * 8;
    const unsigned short* Bp = sel ? Bp1 : Bp0;
    unsigned short* C = sel ? C1 : C0;

    float4v acc[4];
    #pragma unroll
    for (int ni = 0; ni < 4; ++ni) acc[ni] = (float4v)(0.0f);

    for (int kb = 0; kb < 8; ++kb) {
        short8 af = *(const short8*)(A + (size_t)(m0 + l15) * 256 + kb * 32 + koff);
        short8 bf[4];
        #pragma unroll
        for (int ni = 0; ni < 4; ++ni)
            bf[ni] = *(const short8*)(Bp + ((size_t)kb * 256 + n0 + ni * 16 + l15) * 32 + koff);
        #pragma unroll
        for (int ni = 0; ni < 4; ++ni)
            acc[ni] = __builtin_amdgcn_mfma_f32_16x16x32_bf16(af, bf[ni], acc[ni], 0, 0, 0);
    }

    #pragma unroll
    for (int ni = 0; ni < 4; ++ni) {
        int col = n0 + ni * 16 + l15;
        float bv = sel ? 0.f : bias0[col];
        #pragma unroll
        for (int r = 0; r < 4; ++r)
            C[(size_t)(m0 + quad * 4 + r) * 256 + col] = f2bf(acc[ni][r] + bv);
    }
}

// ---------------------------------------------------------------------------
// colsum: Ssc[g,c] = 0.01*( sum_j relu(U[g,c]+Hs[b,j,c]) - relu(U[g,c]+Hs[b,i,c]) )
// ---------------------------------------------------------------------------
__global__ __launch_bounds__(256) void colsum_kernel(
        const unsigned short* __restrict__ U, const unsigned short* __restrict__ Hs,
        unsigned short* __restrict__ Ssc) {
    const int g = blockIdx.x;
    const int b = g / 100, i = g - b * 100;
    const int c = threadIdx.x;
    const float u = bf2f(U[(size_t)g * 256 + c]);
    const unsigned short* base = Hs + (size_t)b * 100 * 256 + c;
    float s = 0.f;
    #pragma unroll 4
    for (int j = 0; j < 100; ++j) {
        float v = u + bf2f(base[(size_t)j * 256]);
        s += (v > 0.f ? v : 0.f);
    }
    float vi = u + bf2f(base[(size_t)i * 256]);
    s -= (vi > 0.f ? vi : 0.f);
    Ssc[(size_t)g * 256 + c] = f2bf(s * 0.01f);
}

// ---------------------------------------------------------------------------
// Phase B: grid (3200,2), block 256 (4 waves x 64 cols), M=64 (<=50 real).
// K-loop: t2 A-frags built in regs = relu(U_i + Hs_j); B = Wpz (L2).
// z4 = relu(C4_i + Vs_j + acc) -> LDS (bf16, C-layout); barrier;
// projection: per-wave 16 rows, 8 MFMA vs Wfp (16-col padded w4b@wo);
// D lanes l15<4 store out fp32 (+bfv). LDS 64x264x2 = 33792 B -> 4 blk/CU.
// ---------------------------------------------------------------------------
__global__ __launch_bounds__(256, 4) void edge_phaseB_kernel(
        const unsigned short* __restrict__ Hs, const unsigned short* __restrict__ Vs,
        const unsigned short* __restrict__ U, const unsigned short* __restrict__ C4,
        const unsigned short* __restrict__ Wpz, const unsigned short* __restrict__ Wfp,
        const float* __restrict__ bfv,
        float* __restrict__ out) {
    __shared__ __align__(16) unsigned short z4s[64 * 264]; // 33792 B
    const int g = blockIdx.x, hb = blockIdx.y;
    const int b = g / 100, nr = g - b * 100;
    const int nrows = hb ? 49 : 50;
    const int k0 = hb * 50;
    const int tid  = threadIdx.x;
    const int wave = tid >> 6;
    const int lane = tid & 63;
    const int l15  = lane & 15;
    const int quad = lane >> 4;
    const int n0   = wave * 64;
    const int koff = quad * 8;

    int jrow[4];                         // A-side gather rows (indexed by l15)
    #pragma unroll
    for (int mi = 0; mi < 4; ++mi) {
        int local = mi * 16 + l15;
        int k = k0 + local;
        int j = (local < nrows) ? (k + (k >= nr ? 1 : 0)) : 0;
        jrow[mi] = b * 100 + j;
    }

    float c4v[4];
    #pragma unroll
    for (int ni = 0; ni < 4; ++ni)
        c4v[ni] = bf2f(C4[(size_t)g * 256 + n0 + ni * 16 + l15]);

    float4v acc[4][4];
    #pragma unroll
    for (int mi = 0; mi < 4; ++mi)
        #pragma unroll
        for (int ni = 0; ni < 4; ++ni) acc[mi][ni] = (float4v)(0.0f);

    const unsigned short* Ug = U + (size_t)g * 256;
    #pragma unroll
    for (int kb = 0; kb < 8; ++kb) {
        short8 uf = *(const short8*)(Ug + kb * 32 + koff);
        float u[8];
        #pragma unroll
        for (int e = 0; e < 8; ++e) u[e] = bf2f((unsigned short)uf[e]);
        short8 af[4], bf[4];
        #pragma unroll
        for (int mi = 0; mi < 4; ++mi) {
            short8 hf = *(const short8*)(Hs + (size_t)jrow[mi] * 256 + kb * 32 + koff);
            short8 t;
            #pragma unroll
            for (int e = 0; e < 8; ++e) {
                float v = u[e] + bf2f((unsigned short)hf[e]);
                t[e] = (short)f2bf(v > 0.f ? v : 0.f);
            }
            af[mi] = t;
        }
        #pragma unroll
        for (int ni = 0; ni < 4; ++ni)
            bf[ni] = *(const short8*)(Wpz + ((size_t)kb * 256 + n0 + ni * 16 + l15) * 32 + koff);
        #pragma unroll
        for (int mi = 0; mi < 4; ++mi)
            #pragma unroll
            for (int ni = 0; ni < 4; ++ni)
                acc[mi][ni] = __builtin_amdgcn_mfma_f32_16x16x32_bf16(af[mi], bf[ni], acc[mi][ni], 0, 0, 0);
    }

    // ---- z4 = relu(C4_i + Vs_j + acc) -> LDS (C-layout) ----
    #pragma unroll
    for (int mi = 0; mi < 4; ++mi) {
        #pragma unroll
        for (int r = 0; r < 4; ++r) {
            int row = mi * 16 + quad * 4 + r;          // local edge idx (C-layout)
            int k = k0 + row;
            int j = (row < nrows) ? (k + (k >= nr ? 1 : 0)) : 0;
            const unsigned short* vsr = Vs + (size_t)(b * 100 + j) * 256;
            #pragma unroll
            for (int ni = 0; ni < 4; ++ni) {
                int col = n0 + ni * 16 + l15;
                float zv = c4v[ni] + bf2f(vsr[col]) + acc[mi][ni][r];
                zv = zv > 0.f ? zv : 0.f;
                z4s[row * 264 + col] = f2bf(zv);
            }
        }
    }
    __syncthreads();

    // ---- projection: wave handles rows wave*16..+15; 8 MFMA vs Wfp ----
    float4v pacc = (float4v)(0.0f);
    #pragma unroll
    for (int kb = 0; kb < 8; ++kb) {
        short8 za = *(const short8*)(&z4s[(wave * 16 + l15) * 264 + kb * 32 + koff]);
        short8 wb = *(const short8*)(Wfp + (size_t)kb * 512 + l15 * 32 + koff);
        pacc = __builtin_amdgcn_mfma_f32_16x16x32_bf16(za, wb, pacc, 0, 0, 0);
    }

    if (l15 < 4) {
        float bv = bfv[l15];
        #pragma unroll
        for (int r = 0; r < 4; ++r) {
            int row = wave * 16 + quad * 4 + r;
            if (row < nrows)
                out[((size_t)b * 9900 + nr * 99 + k0 + row) * 4 + l15] = pacc[r] + bv;
        }
    }
}

extern "C" void kernel_launch(void* const* d_in, const int* in_sizes, int n_in,
                              void* d_out, int out_size, void* d_ws, size_t ws_size,
                              hipStream_t stream) {
    const float* x   = (const float*)d_in[0];
    const float* w1a = (const float*)d_in[3];
    const float* b1a = (const float*)d_in[4];
    const float* w1b = (const float*)d_in[5];
    const float* b1b = (const float*)d_in[6];
    const float* w2a = (const float*)d_in[7];
    const float* b2a = (const float*)d_in[8];
    const float* w2b = (const float*)d_in[9];
    const float* b2b = (const float*)d_in[10];
    const float* w3a = (const float*)d_in[11];
    const float* b3a = (const float*)d_in[12];
    const float* w3b = (const float*)d_in[13];
    const float* b3b = (const float*)d_in[14];
    const float* w4a = (const float*)d_in[15];
    const float* b4a = (const float*)d_in[16];
    const float* w4b = (const float*)d_in[17];
    const float* b4b = (const float*)d_in[18];
    const float* wo  = (const float*)d_in[19];
    const float* bo  = (const float*)d_in[20];
    float* out = (float*)d_out;
    (void)in_sizes; (void)n_in; (void)out_size; (void)ws_size;

    char* ws = (char*)d_ws;
    size_t off = 0;
    auto alloc = [&](size_t bytes) {
        size_t o = off;
        off = (off + bytes + 255) & ~(size_t)255;
        return o;
    };
    const size_t SLOT_BF = (size_t)3200 * 256 * 2;   // 1.64 MB
    unsigned short* S_h  = (unsigned short*)(ws + alloc(SLOT_BF)); // h
    unsigned short* S_U  = (unsigned short*)(ws + alloc(SLOT_BF)); // U
    unsigned short* S_Hs = (unsigned short*)(ws + alloc(SLOT_BF)); // Hs
    unsigned short* S_Vs = (unsigned short*)(ws + alloc(SLOT_BF)); // Vs
    unsigned short* S_3  = (unsigned short*)(ws + alloc(SLOT_BF)); // t1 -> vin -> v2
    unsigned short* S_4  = (unsigned short*)(ws + alloc(SLOT_BF)); // hin -> Ssc -> t3 -> C4
    unsigned short* Wp1a = (unsigned short*)(ws + alloc(224 * 256 * 2));
    unsigned short* Wp1b = (unsigned short*)(ws + alloc(256 * 256 * 2));
    unsigned short* Wp2r = (unsigned short*)(ws + alloc(256 * 256 * 2));
    unsigned short* Wp2s = (unsigned short*)(ws + alloc(256 * 256 * 2));
    unsigned short* Wp2b = (unsigned short*)(ws + alloc(256 * 256 * 2));
    unsigned short* Wp3a = (unsigned short*)(ws + alloc(256 * 256 * 2));
    unsigned short* Wp3b = (unsigned short*)(ws + alloc(256 * 256 * 2));
    unsigned short* Wp4r = (unsigned short*)(ws + alloc(256 * 256 * 2));
    unsigned short* Wp4s = (unsigned short*)(ws + alloc(256 * 256 * 2));
    unsigned short* Wpz  = (unsigned short*)(ws + alloc(256 * 256 * 2));
    unsigned short* Wfp  = (unsigned short*)(ws + alloc(8 * 16 * 32 * 2));
    float*          bfv  = (float*)(ws + alloc(4 * 4));
    float*          b4ap = (float*)(ws + alloc(256 * 4));
    float*          b2bs = (float*)(ws + alloc(256 * 4));
    // total ~11.13 MB (<= 11.2 proven safe)

    unsigned short* hin = S_4;   // [prep, g1]
    unsigned short* Ssc = S_4;   // [colsum, g4]
    unsigned short* t3  = S_4;   // [g5, g6]
    unsigned short* C4  = S_4;   // [g7d, phaseB]
    unsigned short* t1  = S_3;   // [g1, g2]
    unsigned short* vin = S_3;   // [g4, g5]
    unsigned short* v2  = S_3;   // [g6, g7d]

    // ---- prep (1 launch: packs + fusions + repack) ----
    hipLaunchKernelGGL(prep_kernel, dim3(5330), dim3(256), 0, stream,
                       x, w1a, w1b, w2a, w2b, w3a, w3b, w4a, b4a, w4b, b4b, wo, bo, b2b,
                       Wp1a, Wp1b, Wp2r, Wp2s, Wp2b, Wp3a, Wp3b, Wp4r, Wp4s, Wpz,
                       Wfp, bfv, b4ap, b2bs, hin);

    // ---- node MLP1, then U & Hs (dual) ----
    hipLaunchKernelGGL((node_gemm_kernel<true >), dim3(100, 4), dim3(128), 0, stream, hin, Wp1a, b1a, t1,  224); // g1
    hipLaunchKernelGGL((node_gemm_kernel<false>), dim3(100, 4), dim3(128), 0, stream, t1,  Wp1b, b1b, S_h, 256); // g2
    hipLaunchKernelGGL(node_gemm_dual_kernel, dim3(100, 8), dim3(128), 0, stream,
                       S_h, Wp2r, b2a, S_U, Wp2s, S_Hs);                                                          // g3d
    // ---- colsum (edge aggregation without GEMM) ----
    hipLaunchKernelGGL(colsum_kernel, dim3(3200), dim3(256), 0, stream, S_U, S_Hs, Ssc);
    // ---- vin + node MLP3, then C4 & Vs (dual) ----
    hipLaunchKernelGGL((node_gemm_kernel<false>), dim3(100, 4), dim3(128), 0, stream, Ssc, Wp2b, b2bs, vin, 256); // g4
    hipLaunchKernelGGL((node_gemm_kernel<true >), dim3(100, 4), dim3(128), 0, stream, vin, Wp3a, b3a,  t3,  256); // g5
    hipLaunchKernelGGL((node_gemm_kernel<false>), dim3(100, 4), dim3(128), 0, stream, t3,  Wp3b, b3b,  v2,  256); // g6
    hipLaunchKernelGGL(node_gemm_dual_kernel, dim3(100, 8), dim3(128), 0, stream,
                       v2, Wp4r, b4ap, C4, Wp4s, S_Vs);                                                           // g7d
    // ---- phase B (in-reg t2, K=256 GEMM, MFMA projection) ----
    hipLaunchKernelGGL(edge_phaseB_kernel, dim3(3200, 2), dim3(256), 0, stream,
                       S_Hs, S_Vs, S_U, C4, Wpz, Wfp, bfv, out);
}

// Round 9
// 335.100 us; speedup vs baseline: 1.5100x; 1.5100x over previous
//
#include <hip/hip_runtime.h>
#include <hip/hip_bf16.h>
#include <stdint.h>

// ---------------------------------------------------------------------------
// NRI-style MLP encoder. B=32, T=50, N=100, D=4, E=9900, H=256. fp32 I/O.
// R7 formulation (send terms are node GEMMs; only edge GEMM is K=256 t2@Wpz).
// R9 = R8 with the spill fixed: R8's __launch_bounds__(256,4) capped unified
// VGPR+AGPR at 128 (acc=64 AGPR + 64 arch = exactly the cap) -> ~510 B/thread
// scratch spill (WRITE_SIZE 836 MB, hbm 3.5 TB/s). Now (256,3): 170-reg cap,
// ~150 live -> no spill, 3 blk/CU (LDS would allow 4). c4v load moved after
// K-loop to shrink the live set.
// ---------------------------------------------------------------------------

typedef __attribute__((ext_vector_type(8))) short short8;
typedef __attribute__((ext_vector_type(4))) float float4v;

__device__ inline float bf2f(unsigned short u) {
    union { unsigned int i; float f; } v; v.i = ((unsigned int)u) << 16; return v.f;
}
__device__ inline unsigned short f2bf(float f) {
    union { float f; unsigned int i; } v; v.f = f;
    unsigned int i = v.i;
    return (unsigned short)((i + 0x7FFFu + ((i >> 16) & 1u)) >> 16);
}

// ---------------------------------------------------------------------------
// MEGA-PREP: bx<2272 weight packs | <2528 Wpz=pack(w2b@w4a_e) | <2530 misc
// (Wfp/bfv/b4ap/b2bs) | rest repack x. fp32 in, bf16 packed out.
// ---------------------------------------------------------------------------
__global__ __launch_bounds__(256) void prep_kernel(
        const float* __restrict__ x,
        const float* __restrict__ w1a, const float* __restrict__ w1b,
        const float* __restrict__ w2a, const float* __restrict__ w2b,
        const float* __restrict__ w3a, const float* __restrict__ w3b,
        const float* __restrict__ w4a, const float* __restrict__ b4a,
        const float* __restrict__ w4b, const float* __restrict__ b4b,
        const float* __restrict__ wo,  const float* __restrict__ bo,
        const float* __restrict__ b2b,
        unsigned short* __restrict__ Wp1a, unsigned short* __restrict__ Wp1b,
        unsigned short* __restrict__ Wp2r, unsigned short* __restrict__ Wp2s,
        unsigned short* __restrict__ Wp2b, unsigned short* __restrict__ Wp3a,
        unsigned short* __restrict__ Wp3b, unsigned short* __restrict__ Wp4r,
        unsigned short* __restrict__ Wp4s, unsigned short* __restrict__ Wpz,
        unsigned short* __restrict__ Wfp, float* __restrict__ bfv,
        float* __restrict__ b4ap, float* __restrict__ b2bs,
        unsigned short* __restrict__ hin) {
    int bx = blockIdx.x;
    int tid = threadIdx.x;
    if (bx < 2272) {
        const float* W; unsigned short* Wp; int Kin; int b0;
        if      (bx <  224) { W = w1a;             Wp = Wp1a; Kin = 200; b0 = 0;    }
        else if (bx <  480) { W = w1b;             Wp = Wp1b; Kin = 256; b0 = 224;  }
        else if (bx <  736) { W = w2a;             Wp = Wp2r; Kin = 256; b0 = 480;  }
        else if (bx <  992) { W = w2a + 256 * 256; Wp = Wp2s; Kin = 256; b0 = 736;  }
        else if (bx < 1248) { W = w2b;             Wp = Wp2b; Kin = 256; b0 = 992;  }
        else if (bx < 1504) { W = w3a;             Wp = Wp3a; Kin = 256; b0 = 1248; }
        else if (bx < 1760) { W = w3b;             Wp = Wp3b; Kin = 256; b0 = 1504; }
        else if (bx < 2016) { W = w4a;             Wp = Wp4r; Kin = 256; b0 = 1760; }
        else                { W = w4a + 256 * 256; Wp = Wp4s; Kin = 256; b0 = 2016; }
        int idx = (bx - b0) * 256 + tid;
        int k = idx >> 8, n = idx & 255;
        unsigned short v = (k < Kin) ? f2bf(W[k * 256 + n]) : (unsigned short)0;
        Wp[((size_t)(k >> 5) * 256 + n) * 32 + (k & 31)] = v;
    } else if (bx < 2528) {
        int k = bx - 2272, c = tid;
        float s = 0.f;
        for (int t = 0; t < 256; ++t)
            s += w2b[k * 256 + t] * w4a[(size_t)(512 + t) * 256 + c];
        Wpz[((size_t)(k >> 5) * 256 + c) * 32 + (k & 31)] = f2bf(s);
    } else if (bx < 2530) {
        int k = tid;
        if (bx == 2528) {
            float a[4] = {0.f, 0.f, 0.f, 0.f};
            for (int c = 0; c < 256; ++c) {
                float wv = w4b[k * 256 + c];
                #pragma unroll
                for (int o = 0; o < 4; ++o) a[o] += wv * wo[c * 4 + o];
            }
            #pragma unroll
            for (int n = 0; n < 16; ++n)
                Wfp[(size_t)(k >> 5) * 512 + n * 32 + (k & 31)] =
                    (n < 4) ? f2bf(a[n]) : (unsigned short)0;
            if (k < 4) {
                float s = bo[k];
                for (int c = 0; c < 256; ++c) s += b4b[c] * wo[c * 4 + k];
                bfv[k] = s;
            }
        } else {
            float s = b4a[k];
            for (int t = 0; t < 256; ++t)
                s += b2b[t] * w4a[(size_t)(512 + t) * 256 + k];
            b4ap[k] = s;
            b2bs[k] = 0.99f * b2b[k];
        }
    } else {
        int idx = (bx - 2530) * 256 + tid;
        if (idx < 3200 * 224) {
            int row = idx / 224;
            int c = idx - row * 224;
            int b = row / 100, n = row - b * 100;
            unsigned short v = 0;
            if (c < 200) {
                int t = c >> 2, d = c & 3;
                v = f2bf(x[(((size_t)(b * 50 + t)) * 100 + n) * 4 + d]);
            }
            hin[(size_t)row * 224 + c] = v;
        }
    }
}

// ---------------------------------------------------------------------------
// Node GEMM: C = act(A@Wp + bias). Grid (100,4), block 128.
// ---------------------------------------------------------------------------
template <bool RELU>
__global__ __launch_bounds__(128) void node_gemm_kernel(
        const unsigned short* __restrict__ A,
        const unsigned short* __restrict__ Bp,
        const float* __restrict__ bias,
        unsigned short* __restrict__ C, int K) {
    const int tid  = threadIdx.x;
    const int wave = tid >> 6;
    const int lane = tid & 63;
    const int l15  = lane & 15;
    const int quad = lane >> 4;
    const int m0   = blockIdx.x * 32 + wave * 16;
    const int n0   = blockIdx.y * 64;
    const int koff = quad * 8;

    float4v acc[4];
    #pragma unroll
    for (int ni = 0; ni < 4; ++ni) acc[ni] = (float4v)(0.0f);

    const int KB = K >> 5;
    for (int kb = 0; kb < KB; ++kb) {
        short8 af = *(const short8*)(A + (size_t)(m0 + l15) * K + kb * 32 + koff);
        short8 bf[4];
        #pragma unroll
        for (int ni = 0; ni < 4; ++ni)
            bf[ni] = *(const short8*)(Bp + ((size_t)kb * 256 + n0 + ni * 16 + l15) * 32 + koff);
        #pragma unroll
        for (int ni = 0; ni < 4; ++ni)
            acc[ni] = __builtin_amdgcn_mfma_f32_16x16x32_bf16(af, bf[ni], acc[ni], 0, 0, 0);
    }

    #pragma unroll
    for (int ni = 0; ni < 4; ++ni) {
        int col = n0 + ni * 16 + l15;
        float bv = bias[col];
        #pragma unroll
        for (int r = 0; r < 4; ++r) {
            float v = acc[ni][r] + bv;
            if (RELU) v = v > 0.f ? v : 0.f;
            C[(size_t)(m0 + quad * 4 + r) * 256 + col] = f2bf(v);
        }
    }
}

// ---- dual node GEMM (shared A, K=256): y<4 -> C0=A@Bp0+bias0; y>=4 -> C1=A@Bp1 ----
__global__ __launch_bounds__(128) void node_gemm_dual_kernel(
        const unsigned short* __restrict__ A,
        const unsigned short* __restrict__ Bp0, const float* __restrict__ bias0,
        unsigned short* __restrict__ C0,
        const unsigned short* __restrict__ Bp1, unsigned short* __restrict__ C1) {
    const int tid  = threadIdx.x;
    const int wave = tid >> 6;
    const int lane = tid & 63;
    const int l15  = lane & 15;
    const int quad = lane >> 4;
    const int m0   = blockIdx.x * 32 + wave * 16;
    const int sel  = blockIdx.y >> 2;
    const int n0   = (blockIdx.y & 3) * 64;
    const int koff = quad * 8;
    const unsigned short* Bp = sel ? Bp1 : Bp0;
    unsigned short* C = sel ? C1 : C0;

    float4v acc[4];
    #pragma unroll
    for (int ni = 0; ni < 4; ++ni) acc[ni] = (float4v)(0.0f);

    for (int kb = 0; kb < 8; ++kb) {
        short8 af = *(const short8*)(A + (size_t)(m0 + l15) * 256 + kb * 32 + koff);
        short8 bf[4];
        #pragma unroll
        for (int ni = 0; ni < 4; ++ni)
            bf[ni] = *(const short8*)(Bp + ((size_t)kb * 256 + n0 + ni * 16 + l15) * 32 + koff);
        #pragma unroll
        for (int ni = 0; ni < 4; ++ni)
            acc[ni] = __builtin_amdgcn_mfma_f32_16x16x32_bf16(af, bf[ni], acc[ni], 0, 0, 0);
    }

    #pragma unroll
    for (int ni = 0; ni < 4; ++ni) {
        int col = n0 + ni * 16 + l15;
        float bv = sel ? 0.f : bias0[col];
        #pragma unroll
        for (int r = 0; r < 4; ++r)
            C[(size_t)(m0 + quad * 4 + r) * 256 + col] = f2bf(acc[ni][r] + bv);
    }
}

// ---------------------------------------------------------------------------
// colsum: Ssc[g,c] = 0.01*( sum_j relu(U[g,c]+Hs[b,j,c]) - relu(U[g,c]+Hs[b,i,c]) )
// ---------------------------------------------------------------------------
__global__ __launch_bounds__(256) void colsum_kernel(
        const unsigned short* __restrict__ U, const unsigned short* __restrict__ Hs,
        unsigned short* __restrict__ Ssc) {
    const int g = blockIdx.x;
    const int b = g / 100, i = g - b * 100;
    const int c = threadIdx.x;
    const float u = bf2f(U[(size_t)g * 256 + c]);
    const unsigned short* base = Hs + (size_t)b * 100 * 256 + c;
    float s = 0.f;
    #pragma unroll 4
    for (int j = 0; j < 100; ++j) {
        float v = u + bf2f(base[(size_t)j * 256]);
        s += (v > 0.f ? v : 0.f);
    }
    float vi = u + bf2f(base[(size_t)i * 256]);
    s -= (vi > 0.f ? vi : 0.f);
    Ssc[(size_t)g * 256 + c] = f2bf(s * 0.01f);
}

// ---------------------------------------------------------------------------
// Phase B: grid (3200,2), block 256 (4 waves x 64 cols), M=64 (<=50 real).
// K-loop: t2 A-frags built in regs = relu(U_i + Hs_j); B = Wpz (L2).
// z4 = relu(C4_i + Vs_j + acc) -> LDS (bf16, C-layout); barrier;
// projection: per-wave 16 rows, 8 MFMA vs Wfp; lanes l15<4 store fp32 out.
// LDS 33792 B. __launch_bounds__(256,3): 170-reg cap (NO spill; (256,4)'s
// 128 cap caused 836 MB/launch scratch traffic in R8).
// ---------------------------------------------------------------------------
__global__ __launch_bounds__(256, 3) void edge_phaseB_kernel(
        const unsigned short* __restrict__ Hs, const unsigned short* __restrict__ Vs,
        const unsigned short* __restrict__ U, const unsigned short* __restrict__ C4,
        const unsigned short* __restrict__ Wpz, const unsigned short* __restrict__ Wfp,
        const float* __restrict__ bfv,
        float* __restrict__ out) {
    __shared__ __align__(16) unsigned short z4s[64 * 264]; // 33792 B
    const int g = blockIdx.x, hb = blockIdx.y;
    const int b = g / 100, nr = g - b * 100;
    const int nrows = hb ? 49 : 50;
    const int k0 = hb * 50;
    const int tid  = threadIdx.x;
    const int wave = tid >> 6;
    const int lane = tid & 63;
    const int l15  = lane & 15;
    const int quad = lane >> 4;
    const int n0   = wave * 64;
    const int koff = quad * 8;

    int jrow[4];                         // A-side gather rows (indexed by l15)
    #pragma unroll
    for (int mi = 0; mi < 4; ++mi) {
        int local = mi * 16 + l15;
        int k = k0 + local;
        int j = (local < nrows) ? (k + (k >= nr ? 1 : 0)) : 0;
        jrow[mi] = b * 100 + j;
    }

    float4v acc[4][4];
    #pragma unroll
    for (int mi = 0; mi < 4; ++mi)
        #pragma unroll
        for (int ni = 0; ni < 4; ++ni) acc[mi][ni] = (float4v)(0.0f);

    const unsigned short* Ug = U + (size_t)g * 256;
    #pragma unroll
    for (int kb = 0; kb < 8; ++kb) {
        short8 uf = *(const short8*)(Ug + kb * 32 + koff);
        short8 af[4], bf[4];
        #pragma unroll
        for (int mi = 0; mi < 4; ++mi) {
            short8 hf = *(const short8*)(Hs + (size_t)jrow[mi] * 256 + kb * 32 + koff);
            short8 t;
            #pragma unroll
            for (int e = 0; e < 8; ++e) {
                float v = bf2f((unsigned short)uf[e]) + bf2f((unsigned short)hf[e]);
                t[e] = (short)f2bf(v > 0.f ? v : 0.f);
            }
            af[mi] = t;
        }
        #pragma unroll
        for (int ni = 0; ni < 4; ++ni)
            bf[ni] = *(const short8*)(Wpz + ((size_t)kb * 256 + n0 + ni * 16 + l15) * 32 + koff);
        #pragma unroll
        for (int mi = 0; mi < 4; ++mi)
            #pragma unroll
            for (int ni = 0; ni < 4; ++ni)
                acc[mi][ni] = __builtin_amdgcn_mfma_f32_16x16x32_bf16(af[mi], bf[ni], acc[mi][ni], 0, 0, 0);
    }

    // ---- z4 = relu(C4_i + Vs_j + acc) -> LDS (C-layout) ----
    float c4v[4];
    #pragma unroll
    for (int ni = 0; ni < 4; ++ni)
        c4v[ni] = bf2f(C4[(size_t)g * 256 + n0 + ni * 16 + l15]);
    #pragma unroll
    for (int mi = 0; mi < 4; ++mi) {
        #pragma unroll
        for (int r = 0; r < 4; ++r) {
            int row = mi * 16 + quad * 4 + r;          // local edge idx (C-layout)
            int k = k0 + row;
            int j = (row < nrows) ? (k + (k >= nr ? 1 : 0)) : 0;
            const unsigned short* vsr = Vs + (size_t)(b * 100 + j) * 256;
            #pragma unroll
            for (int ni = 0; ni < 4; ++ni) {
                int col = n0 + ni * 16 + l15;
                float zv = c4v[ni] + bf2f(vsr[col]) + acc[mi][ni][r];
                zv = zv > 0.f ? zv : 0.f;
                z4s[row * 264 + col] = f2bf(zv);
            }
        }
    }
    __syncthreads();

    // ---- projection: wave handles rows wave*16..+15; 8 MFMA vs Wfp ----
    float4v pacc = (float4v)(0.0f);
    #pragma unroll
    for (int kb = 0; kb < 8; ++kb) {
        short8 za = *(const short8*)(&z4s[(wave * 16 + l15) * 264 + kb * 32 + koff]);
        short8 wb = *(const short8*)(Wfp + (size_t)kb * 512 + l15 * 32 + koff);
        pacc = __builtin_amdgcn_mfma_f32_16x16x32_bf16(za, wb, pacc, 0, 0, 0);
    }

    if (l15 < 4) {
        float bv = bfv[l15];
        #pragma unroll
        for (int r = 0; r < 4; ++r) {
            int row = wave * 16 + quad * 4 + r;
            if (row < nrows)
                out[((size_t)b * 9900 + nr * 99 + k0 + row) * 4 + l15] = pacc[r] + bv;
        }
    }
}

extern "C" void kernel_launch(void* const* d_in, const int* in_sizes, int n_in,
                              void* d_out, int out_size, void* d_ws, size_t ws_size,
                              hipStream_t stream) {
    const float* x   = (const float*)d_in[0];
    const float* w1a = (const float*)d_in[3];
    const float* b1a = (const float*)d_in[4];
    const float* w1b = (const float*)d_in[5];
    const float* b1b = (const float*)d_in[6];
    const float* w2a = (const float*)d_in[7];
    const float* b2a = (const float*)d_in[8];
    const float* w2b = (const float*)d_in[9];
    const float* b2b = (const float*)d_in[10];
    const float* w3a = (const float*)d_in[11];
    const float* b3a = (const float*)d_in[12];
    const float* w3b = (const float*)d_in[13];
    const float* b3b = (const float*)d_in[14];
    const float* w4a = (const float*)d_in[15];
    const float* b4a = (const float*)d_in[16];
    const float* w4b = (const float*)d_in[17];
    const float* b4b = (const float*)d_in[18];
    const float* wo  = (const float*)d_in[19];
    const float* bo  = (const float*)d_in[20];
    float* out = (float*)d_out;
    (void)in_sizes; (void)n_in; (void)out_size; (void)ws_size;

    char* ws = (char*)d_ws;
    size_t off = 0;
    auto alloc = [&](size_t bytes) {
        size_t o = off;
        off = (off + bytes + 255) & ~(size_t)255;
        return o;
    };
    const size_t SLOT_BF = (size_t)3200 * 256 * 2;   // 1.64 MB
    unsigned short* S_h  = (unsigned short*)(ws + alloc(SLOT_BF)); // h
    unsigned short* S_U  = (unsigned short*)(ws + alloc(SLOT_BF)); // U
    unsigned short* S_Hs = (unsigned short*)(ws + alloc(SLOT_BF)); // Hs
    unsigned short* S_Vs = (unsigned short*)(ws + alloc(SLOT_BF)); // Vs
    unsigned short* S_3  = (unsigned short*)(ws + alloc(SLOT_BF)); // t1 -> vin -> v2
    unsigned short* S_4  = (unsigned short*)(ws + alloc(SLOT_BF)); // hin -> Ssc -> t3 -> C4
    unsigned short* Wp1a = (unsigned short*)(ws + alloc(224 * 256 * 2));
    unsigned short* Wp1b = (unsigned short*)(ws + alloc(256 * 256 * 2));
    unsigned short* Wp2r = (unsigned short*)(ws + alloc(256 * 256 * 2));
    unsigned short* Wp2s = (unsigned short*)(ws + alloc(256 * 256 * 2));
    unsigned short* Wp2b = (unsigned short*)(ws + alloc(256 * 256 * 2));
    unsigned short* Wp3a = (unsigned short*)(ws + alloc(256 * 256 * 2));
    unsigned short* Wp3b = (unsigned short*)(ws + alloc(256 * 256 * 2));
    unsigned short* Wp4r = (unsigned short*)(ws + alloc(256 * 256 * 2));
    unsigned short* Wp4s = (unsigned short*)(ws + alloc(256 * 256 * 2));
    unsigned short* Wpz  = (unsigned short*)(ws + alloc(256 * 256 * 2));
    unsigned short* Wfp  = (unsigned short*)(ws + alloc(8 * 16 * 32 * 2));
    float*          bfv  = (float*)(ws + alloc(4 * 4));
    float*          b4ap = (float*)(ws + alloc(256 * 4));
    float*          b2bs = (float*)(ws + alloc(256 * 4));
    // total ~11.13 MB (<= 11.2 proven safe)

    unsigned short* hin = S_4;   // [prep, g1]
    unsigned short* Ssc = S_4;   // [colsum, g4]
    unsigned short* t3  = S_4;   // [g5, g6]
    unsigned short* C4  = S_4;   // [g7d, phaseB]
    unsigned short* t1  = S_3;   // [g1, g2]
    unsigned short* vin = S_3;   // [g4, g5]
    unsigned short* v2  = S_3;   // [g6, g7d]

    // ---- prep (1 launch: packs + fusions + repack) ----
    hipLaunchKernelGGL(prep_kernel, dim3(5330), dim3(256), 0, stream,
                       x, w1a, w1b, w2a, w2b, w3a, w3b, w4a, b4a, w4b, b4b, wo, bo, b2b,
                       Wp1a, Wp1b, Wp2r, Wp2s, Wp2b, Wp3a, Wp3b, Wp4r, Wp4s, Wpz,
                       Wfp, bfv, b4ap, b2bs, hin);

    // ---- node MLP1, then U & Hs (dual) ----
    hipLaunchKernelGGL((node_gemm_kernel<true >), dim3(100, 4), dim3(128), 0, stream, hin, Wp1a, b1a, t1,  224); // g1
    hipLaunchKernelGGL((node_gemm_kernel<false>), dim3(100, 4), dim3(128), 0, stream, t1,  Wp1b, b1b, S_h, 256); // g2
    hipLaunchKernelGGL(node_gemm_dual_kernel, dim3(100, 8), dim3(128), 0, stream,
                       S_h, Wp2r, b2a, S_U, Wp2s, S_Hs);                                                          // g3d
    // ---- colsum (edge aggregation without GEMM) ----
    hipLaunchKernelGGL(colsum_kernel, dim3(3200), dim3(256), 0, stream, S_U, S_Hs, Ssc);
    // ---- vin + node MLP3, then C4 & Vs (dual) ----
    hipLaunchKernelGGL((node_gemm_kernel<false>), dim3(100, 4), dim3(128), 0, stream, Ssc, Wp2b, b2bs, vin, 256); // g4
    hipLaunchKernelGGL((node_gemm_kernel<true >), dim3(100, 4), dim3(128), 0, stream, vin, Wp3a, b3a,  t3,  256); // g5
    hipLaunchKernelGGL((node_gemm_kernel<false>), dim3(100, 4), dim3(128), 0, stream, t3,  Wp3b, b3b,  v2,  256); // g6
    hipLaunchKernelGGL(node_gemm_dual_kernel, dim3(100, 8), dim3(128), 0, stream,
                       v2, Wp4r, b4ap, C4, Wp4s, S_Vs);                                                           // g7d
    // ---- phase B (in-reg t2, K=256 GEMM, MFMA projection) ----
    hipLaunchKernelGGL(edge_phaseB_kernel, dim3(3200, 2), dim3(256), 0, stream,
                       S_Hs, S_Vs, S_U, C4, Wpz, Wfp, bfv, out);
}